// Round 9
// baseline (264.247 us; speedup 1.0000x reference)
//
#include <hip/hip_runtime.h>
#include <hip/hip_bf16.h>

typedef __hip_bfloat16 bf16;
typedef short bf16x8 __attribute__((ext_vector_type(8)));   // 8 bf16 = 4 VGPRs (MFMA frag)
typedef float f32x4 __attribute__((ext_vector_type(4)));
typedef short s4 __attribute__((ext_vector_type(4)));

#define LL 2048
#define SS 2048
#define EE 1024
#define HH 16
#define HD 64
#define MM (LL * 2)   // 4096 rows (l*B+b)

static __device__ __forceinline__ short f2bs(float f) {
  bf16 h = __float2bfloat16(f);
  short u;
  __builtin_memcpy(&u, &h, 2);
  return u;
}

// pack 8 f32 -> bf16x8 and store to LDS (one ds_write_b128)
static __device__ __forceinline__ void st8(bf16* p, float4 x, float4 y) {
  bf16x8 v;
  v[0] = f2bs(x.x); v[1] = f2bs(x.y); v[2] = f2bs(x.z); v[3] = f2bs(x.w);
  v[4] = f2bs(y.x); v[5] = f2bs(y.y); v[6] = f2bs(y.z); v[7] = f2bs(y.w);
  *(bf16x8*)p = v;
}

// async global->LDS, 16B per lane. LDS dest must be wave-uniform base + lane*16.
#define GLL16(gp, lp) __builtin_amdgcn_global_load_lds(                        \
    (const __attribute__((address_space(1))) void*)(gp),                       \
    (__attribute__((address_space(3))) void*)(lp), 16, 0, 0)

// ---------------------------------------------------------------------------
// prep: tables (0..255) + mask (256..271) + 4x weight cvt (272..4367) +
// query cvt (4368..8463, 4M elems) + key cvt (8464..12559, 4M elems).
// ROUND-9 FIX of round-8's failure: query/key are 4M elements each (round 8
// converted only 1M and allocated 4MB instead of 8MB). Xqb/Xkb now live in
// D_OUT (16 MB, dead until projo overwrites it) — stream-ordered
// write(prep) -> read(qkv) -> overwrite(projo).
__global__ __launch_bounds__(256) void prep_kernel(
    float2* __restrict__ tab, const unsigned char* __restrict__ m,
    float* __restrict__ mf,
    const float* __restrict__ s0, const float* __restrict__ s1,
    const float* __restrict__ s2, const float* __restrict__ s3,
    bf16* __restrict__ wdst,
    const float* __restrict__ xq, const float* __restrict__ xk,
    bf16* __restrict__ xqb, bf16* __restrict__ xkb) {
  const int bid = blockIdx.x;
  if (bid < 256) {
    int i = bid * 256 + threadIdx.x;   // 2048*32 entries
    int pos = i >> 5, fi = i & 31;
    float freq = expf(-(float)fi * (9.210340371976184f / 32.0f));  // 10000^(-fi/32)
    float ang = (float)pos * freq;
    float s, c;
    sincosf(ang, &s, &c);
    tab[i] = make_float2(c, s);
  } else if (bid < 272) {
    int i = (bid - 256) * 256 + threadIdx.x;
    if (i < 2 * SS) mf[i] = m[i] ? -1e30f : 0.f;
  } else if (bid < 4368) {
    int b2 = bid - 272;
    int sel = b2 >> 10;
    const float* src = (sel == 0) ? s0 : (sel == 1) ? s1 : (sel == 2) ? s2 : s3;
    size_t loc = ((size_t)(b2 & 1023) * 256 + threadIdx.x) * 4;
    float4 v = *(const float4*)(src + loc);
    s4 p;
    p[0] = f2bs(v.x); p[1] = f2bs(v.y); p[2] = f2bs(v.z); p[3] = f2bs(v.w);
    *(s4*)(wdst + (size_t)sel * EE * EE + loc) = p;
  } else {
    int b2 = bid - 4368;                       // 0..8191
    const float* src = (b2 < 4096) ? xq : xk;
    bf16* dst = (b2 < 4096) ? xqb : xkb;
    size_t loc = ((size_t)(b2 & 4095) * 256 + threadIdx.x) * 4;
    float4 v = *(const float4*)(src + loc);
    s4 p;
    p[0] = f2bs(v.x); p[1] = f2bs(v.y); p[2] = f2bs(v.z); p[3] = f2bs(v.w);
    *(s4*)(dst + loc) = p;
  }
}

// ---------------------------------------------------------------------------
// OLD direct-from-global proj (kept only for the small-ws f32 fallback path).
template<int MODE, bool XB16, bool WB16>
__global__ __launch_bounds__(256) void proj_kernel(
    const void* __restrict__ Xv, const void* __restrict__ Wv,
    const float* __restrict__ bias, void* __restrict__ dstv,
    const float2* __restrict__ tab)
{
  const int w = threadIdx.x >> 6;
  const int lane = threadIdx.x & 63;
  const int l15 = lane & 15, quad = lane >> 4;
  const int tm = blockIdx.x * 128 + w * 32;
  const int tn = blockIdx.y * 64;

  const size_t aoff0 = (size_t)(tm + l15) * EE + quad * 8;
  const size_t aoff1 = aoff0 + (size_t)16 * EE;
  const size_t woff  = (size_t)(tn + l15) * EE + quad * 8;

  f32x4 zero4 = {0.f, 0.f, 0.f, 0.f};
  f32x4 acc[2][4];
#pragma unroll
  for (int mi = 0; mi < 2; ++mi)
#pragma unroll
    for (int ni = 0; ni < 4; ++ni) acc[mi][ni] = zero4;

  for (int k0 = 0; k0 < EE; k0 += 32) {
    bf16x8 a0, a1;
    if (XB16 || MODE == 3) {
      const bf16* Xb = (const bf16*)Xv;
      a0 = *(const bf16x8*)(Xb + aoff0 + k0);
      a1 = *(const bf16x8*)(Xb + aoff1 + k0);
    } else {
      const float* Xf = (const float*)Xv;
#pragma unroll
      for (int j = 0; j < 8; ++j) a0[j] = f2bs(Xf[aoff0 + k0 + j]);
#pragma unroll
      for (int j = 0; j < 8; ++j) a1[j] = f2bs(Xf[aoff1 + k0 + j]);
    }
#pragma unroll
    for (int ni = 0; ni < 4; ++ni) {
      bf16x8 bv;
      if (WB16) {
        const bf16* Wb = (const bf16*)Wv;
        bv = *(const bf16x8*)(Wb + woff + (size_t)ni * 16 * EE + k0);
      } else {
        const float* Wf = (const float*)Wv;
#pragma unroll
        for (int j = 0; j < 8; ++j) bv[j] = f2bs(Wf[woff + (size_t)ni * 16 * EE + k0 + j]);
      }
      acc[0][ni] = __builtin_amdgcn_mfma_f32_16x16x32_bf16(a0, bv, acc[0][ni], 0, 0, 0);
      acc[1][ni] = __builtin_amdgcn_mfma_f32_16x16x32_bf16(a1, bv, acc[1][ni], 0, 0, 0);
    }
  }

  float bz[4];
#pragma unroll
  for (int ni = 0; ni < 4; ++ni) bz[ni] = bias[tn + ni * 16 + l15];

#pragma unroll
  for (int mi = 0; mi < 2; ++mi) {
#pragma unroll
    for (int ni = 0; ni < 4; ++ni) {
      const int n = tn + ni * 16 + l15;
#pragma unroll
      for (int r = 0; r < 4; ++r) {
        const int m = tm + mi * 16 + quad * 4 + r;
        float v = acc[mi][ni][r] + bz[ni];
        if (MODE <= 1) {
          float other = __shfl_xor(v, 1, 64);        // pair element (n^1) is in lane^1
          int pos = m >> 1, b = m & 1, d = n & 63, h = n >> 6;
          float2 cs = tab[pos * 32 + (d >> 1)];
          float rv = (d & 1) ? (other * cs.y + v * cs.x) : (v * cs.x - other * cs.y);
          ((bf16*)dstv)[((size_t)(b * HH + h) * LL + pos) * HD + d] = __float2bfloat16(rv);
        } else if (MODE == 2) {
          int pos = m >> 1, b = m & 1, d = n & 63, h = n >> 6;
          ((bf16*)dstv)[((size_t)(b * HH + h) * HD + d) * SS + pos] = __float2bfloat16(v);
        } else {
          ((float*)dstv)[(size_t)m * EE + n] = v;
        }
      }
    }
  }
}

// ---------------------------------------------------------------------------
// ROUND-9 fused QKV (= round-8 structure with correct buffers): 128m x 64n,
// BK=32, grid 1536 = 6/CU, packed zero-conflict LDS. Q/K read PRE-CONVERTED
// bf16 A via gll (packed pre-swizzled source, same map as B — no VALU cvt);
// V keeps the f32 reg-staging path (block-uniform branch on z). Halves A
// bytes for 2 of 3 GEMMs: vmem traffic ~990 -> ~730 MB at the measured
// ~51 B/cy/CU port rate.
__global__ __launch_bounds__(256, 6) void qkv_kernel(
    const bf16* __restrict__ Xqb, const bf16* __restrict__ Xkb,
    const float* __restrict__ Xv, const bf16* __restrict__ Wb,
    const float* __restrict__ bq, const float* __restrict__ bk,
    const float* __restrict__ bv, bf16* __restrict__ Qr,
    bf16* __restrict__ Kr, bf16* __restrict__ Vt,
    const float2* __restrict__ tab)
{
  __shared__ __align__(16) bf16 As[2][4096];   // 128 rows -> 64 lrows x 64 = 8 KB/buf
  __shared__ __align__(16) bf16 Bs[2][2048];   // 64 rows -> 32 lrows x 64 = 4 KB/buf

  const int tid = threadIdx.x;
  const int w = tid >> 6;
  const int lane = tid & 63;
  const int l15 = lane & 15, quad = lane >> 4;
  const int id = blockIdx.x;
  const int z = id >> 9;                 // 0=Q 1=K 2=V
  const int g = id & 511;
  const int tmb = (g & 31) * 128;        // same-A blocks (n varies) land on same XCD
  const int tn  = (g >> 5) * 64;

  const bool ab16 = (z <= 1);            // block-uniform
  const bf16* Xb  = (z == 0) ? Xqb : Xkb;
  const bf16* Wm  = Wb + (size_t)z * EE * EE;
  const float* bias = (z == 0) ? bq : (z == 1) ? bk : bv;
  bf16* dst = (z == 0) ? Qr : (z == 1) ? Kr : Vt;

  // shared pre-swizzled source code (packed layout, same for A-b16 and B):
  const int ub = (lane & 7) ^ (lane >> 3);

  // --- A path 1 (bf16, gll): wave w stages rows w*32..w*32+31 as 2 glls.
  const bf16* gAb0 = Xb + (size_t)(tmb + w * 32 + 2 * (lane >> 3) + (ub >> 2)) * EE
                        + (ub & 3) * 8;
  const bf16* gAb1 = gAb0 + (size_t)16 * EE;

  // --- A path 2 (f32, reg-stage + st8): thread t covers rows ar, ar+64.
  const int ar = tid >> 2;               // 0..63
  const int akc = tid & 3;
  const float* gA0 = Xv + (size_t)(tmb + ar) * EE + akc * 8;
  const float* gA1 = gA0 + (size_t)64 * EE;
  const int aw0 = (ar >> 1) * 64 + (((((ar & 1) << 2) | akc) ^ ((ar >> 1) & 7)) * 8);
  const int aw1 = aw0 + 2048;            // row+64 -> lrow+32, same &7 -> same slot

  // --- B staging: ONE gll/wave (16 n-rows = 8 lrows), pre-swizzled source.
  const bf16* gB = Wm + (size_t)(tn + w * 16 + 2 * (lane >> 3) + (ub >> 2)) * EE
                      + (ub & 3) * 8;

  // fragment read base (A and B share the formula): row = 16*base + l15, kc = quad
  const int arbase = (l15 >> 1) * 64 + (((((l15 & 1) << 2) | quad) ^ (l15 >> 1)) * 8);

  f32x4 zero4 = {0.f, 0.f, 0.f, 0.f};
  f32x4 acc[2][4];
#pragma unroll
  for (int mi = 0; mi < 2; ++mi)
#pragma unroll
    for (int ni = 0; ni < 4; ++ni) acc[mi][ni] = zero4;

  {  // prologue: stage tile 0
    GLL16(gB, (bf16*)&Bs[0][w * 512] + lane * 8);
    if (ab16) {
      GLL16(gAb0, (bf16*)&As[0][w * 1024] + lane * 8);
      GLL16(gAb1, (bf16*)&As[0][w * 1024 + 512] + lane * 8);
    } else {
      float4 a00 = *(const float4*)(gA0);
      float4 a01 = *(const float4*)(gA0 + 4);
      float4 a10 = *(const float4*)(gA1);
      float4 a11 = *(const float4*)(gA1 + 4);
      st8(&As[0][aw0], a00, a01);
      st8(&As[0][aw1], a10, a11);
    }
  }
  __syncthreads();

  for (int t = 0; t < 32; ++t) {
    const int cur = t & 1;
    float4 a00, a01, a10, a11;
    if (t < 31) {                        // issue next-tile loads EARLY (T14)
      const int k0 = (t + 1) * 32;
      GLL16(gB + k0, (bf16*)&Bs[cur ^ 1][w * 512] + lane * 8);
      if (ab16) {
        GLL16(gAb0 + k0, (bf16*)&As[cur ^ 1][w * 1024] + lane * 8);
        GLL16(gAb1 + k0, (bf16*)&As[cur ^ 1][w * 1024 + 512] + lane * 8);
      } else {
        a00 = *(const float4*)(gA0 + k0);
        a01 = *(const float4*)(gA0 + k0 + 4);
        a10 = *(const float4*)(gA1 + k0);
        a11 = *(const float4*)(gA1 + k0 + 4);
      }
    }
    // compute current tile: 8 MFMA/wave (wave = 32m x 64n)
    bf16x8 af0 = *(const bf16x8*)(&As[cur][w * 1024 + arbase]);
    bf16x8 af1 = *(const bf16x8*)(&As[cur][w * 1024 + 512 + arbase]);
#pragma unroll
    for (int ni = 0; ni < 4; ++ni) {
      bf16x8 bfr = *(const bf16x8*)(&Bs[cur][ni * 512 + arbase]);
      acc[0][ni] = __builtin_amdgcn_mfma_f32_16x16x32_bf16(af0, bfr, acc[0][ni], 0, 0, 0);
      acc[1][ni] = __builtin_amdgcn_mfma_f32_16x16x32_bf16(af1, bfr, acc[1][ni], 0, 0, 0);
    }
    if (!ab16 && t < 31) {               // f32 path: cvt+write lands after compute
      st8(&As[cur ^ 1][aw0], a00, a01);
      st8(&As[cur ^ 1][aw1], a10, a11);
    }
    __syncthreads();                     // drains gll + ds_writes + reads
  }

  float bz[4];
#pragma unroll
  for (int ni = 0; ni < 4; ++ni) bz[ni] = bias[tn + ni * 16 + l15];

#pragma unroll
  for (int mi = 0; mi < 2; ++mi) {
#pragma unroll
    for (int ni = 0; ni < 4; ++ni) {
      const int n = tn + ni * 16 + l15;
#pragma unroll
      for (int r = 0; r < 4; ++r) {
        const int m = tmb + w * 32 + mi * 16 + quad * 4 + r;
        float v = acc[mi][ni][r] + bz[ni];
        if (z <= 1) {                    // RoPE epilogue (Q, K)
          float other = __shfl_xor(v, 1, 64);   // pair element (n^1) is in lane^1
          int pos = m >> 1, b = m & 1, d = n & 63, h = n >> 6;
          float2 cs = tab[pos * 32 + (d >> 1)];
          float rv = (d & 1) ? (other * cs.y + v * cs.x) : (v * cs.x - other * cs.y);
          dst[((size_t)(b * HH + h) * LL + pos) * HD + d] = __float2bfloat16(rv);
        } else {                         // V: store transposed [b][h][d][pos]
          int pos = m >> 1, b = m & 1, d = n & 63, h = n >> 6;
          dst[((size_t)(b * HH + h) * HD + d) * SS + pos] = __float2bfloat16(v);
        }
      }
    }
  }
}

// ---------------------------------------------------------------------------
// O-projection — UNCHANGED from round 7 (part of the 251.6 best total).
// 128m x 64n, BK=32, grid (32,16) = 512, packed zero-conflict layout.
__global__ __launch_bounds__(256) void projo_kernel(
    const bf16* __restrict__ X, const bf16* __restrict__ W,
    const float* __restrict__ bias, float* __restrict__ dst)
{
  __shared__ __align__(16) bf16 As[2][4096];    // 8 KB/buf
  __shared__ __align__(16) bf16 Bs[2][2048];    // 4 KB/buf

  const int tid = threadIdx.x;
  const int w = tid >> 6;
  const int lane = tid & 63;
  const int l15 = lane & 15, quad = lane >> 4;
  const int tmb = blockIdx.x * 128;
  const int tn  = blockIdx.y * 64;

  const int ub = (lane & 7) ^ (lane >> 3);
  const bf16* gA0 = X + (size_t)(tmb + w * 32 + 2 * (lane >> 3) + (ub >> 2)) * EE
                       + (ub & 3) * 8;
  const bf16* gA1 = gA0 + (size_t)16 * EE;
  const bf16* gB  = W + (size_t)(tn + w * 16 + 2 * (lane >> 3) + (ub >> 2)) * EE
                       + (ub & 3) * 8;

  const int arbase = (l15 >> 1) * 64 + (((((l15 & 1) << 2) | quad) ^ (l15 >> 1)) * 8);

  f32x4 zero4 = {0.f, 0.f, 0.f, 0.f};
  f32x4 acc[2][4];
#pragma unroll
  for (int mi = 0; mi < 2; ++mi)
#pragma unroll
    for (int ni = 0; ni < 4; ++ni) acc[mi][ni] = zero4;

  GLL16(gA0, (bf16*)&As[0][w * 1024] + lane * 8);
  GLL16(gA1, (bf16*)&As[0][w * 1024 + 512] + lane * 8);
  GLL16(gB,  (bf16*)&Bs[0][w * 512] + lane * 8);
  __syncthreads();

  for (int t = 0; t < 32; ++t) {
    const int cur = t & 1;
    if (t < 31) {
      const int k0 = (t + 1) * 32;
      GLL16(gA0 + k0, (bf16*)&As[cur ^ 1][w * 1024] + lane * 8);
      GLL16(gA1 + k0, (bf16*)&As[cur ^ 1][w * 1024 + 512] + lane * 8);
      GLL16(gB + k0,  (bf16*)&Bs[cur ^ 1][w * 512] + lane * 8);
    }
    bf16x8 af0 = *(const bf16x8*)(&As[cur][w * 1024 + arbase]);
    bf16x8 af1 = *(const bf16x8*)(&As[cur][w * 1024 + 512 + arbase]);
#pragma unroll
    for (int ni = 0; ni < 4; ++ni) {
      bf16x8 bfr = *(const bf16x8*)(&Bs[cur][ni * 512 + arbase]);
      acc[0][ni] = __builtin_amdgcn_mfma_f32_16x16x32_bf16(af0, bfr, acc[0][ni], 0, 0, 0);
      acc[1][ni] = __builtin_amdgcn_mfma_f32_16x16x32_bf16(af1, bfr, acc[1][ni], 0, 0, 0);
    }
    __syncthreads();
  }

  float bz[4];
#pragma unroll
  for (int ni = 0; ni < 4; ++ni) bz[ni] = bias[tn + ni * 16 + l15];

#pragma unroll
  for (int mi = 0; mi < 2; ++mi) {
#pragma unroll
    for (int ni = 0; ni < 4; ++ni) {
      const int n = tn + ni * 16 + l15;
#pragma unroll
      for (int r = 0; r < 4; ++r) {
        const int m = tmb + w * 32 + mi * 16 + quad * 4 + r;
        dst[(size_t)m * EE + n] = acc[mi][ni][r] + bz[ni];
      }
    }
  }
}

// ---------------------------------------------------------------------------
// Flash attention — round-2 byte-identical version (32 q/wave, grid 512,
// measured 67.5-69.8 µs in rounds 2-6).
__global__ __launch_bounds__(256) void attn_kernel(
    const bf16* __restrict__ Qr, const bf16* __restrict__ Kr,
    const bf16* __restrict__ Vt, const float* __restrict__ maskf,
    bf16* __restrict__ ctx)
{
  __shared__ __align__(16) bf16 Ks[2][64 * 64];       // 16 KB: [buf][s][d]
  __shared__ __align__(16) bf16 Vs[2][64 * 64];       // 16 KB: [buf][d][s]
  __shared__ __align__(16) short Plds[4][32][56];     // 14 KB: [wave][q][s str 56]

  const int w = threadIdx.x >> 6;
  const int lane = threadIdx.x & 63;
  const int l15 = lane & 15, quad = lane >> 4;
  const int id = blockIdx.x;
  const int bh = id & 31;             // XCD = bh % 8
  const int qt = id >> 5;             // 0..15
  const int b = bh >> 4, h = bh & 15;
  const int q0 = qt * 128 + w * 32;

  const bf16* Qbh = Qr + (size_t)bh * LL * HD;
  const bf16* Kbh = Kr + (size_t)bh * SS * HD;
  const bf16* Vbh = Vt + (size_t)bh * HD * SS;
  const float* mrow = maskf + b * SS;

  bf16x8 qf[2][2];
#pragma unroll
  for (int mi = 0; mi < 2; ++mi) {
    const bf16* qp = Qbh + (size_t)(q0 + mi * 16 + l15) * HD + quad * 8;
    qf[mi][0] = *(const bf16x8*)(qp);
    qf[mi][1] = *(const bf16x8*)(qp + 32);
  }

  const int srow = lane >> 3;                     // 0..7
  const int gswz = ((lane & 7) ^ srow) * 8;       // source chunk, elems
  const int kswz0 = ((quad    ) ^ (l15 & 7)) * 8;
  const int kswz1 = ((quad + 4) ^ (l15 & 7)) * 8;

#define STAGE(buf, S0) {                                                       \
    _Pragma("unroll")                                                          \
    for (int i = 0; i < 2; ++i) {                                              \
      const int rb = w * 16 + i * 8;                                           \
      GLL16(Kbh + (size_t)((S0) + rb + srow) * HD + gswz,                      \
            (bf16*)&Ks[buf][rb * 64] + lane * 8);                              \
      GLL16(Vbh + (size_t)(rb + srow) * SS + (S0) + gswz,                      \
            (bf16*)&Vs[buf][rb * 64] + lane * 8);                              \
    }                                                                          \
  }

  f32x4 zero4 = {0.f, 0.f, 0.f, 0.f};
  f32x4 o[2][4];
#pragma unroll
  for (int mi = 0; mi < 2; ++mi)
#pragma unroll
    for (int t = 0; t < 4; ++t) o[mi][t] = zero4;
  float ps0 = 0.f, ps1 = 0.f;

  STAGE(0, 0);
  __syncthreads();

  for (int t = 0; t < SS / 64; ++t) {
    const int s0 = t * 64;
    const int cur = t & 1;
    if (t + 1 < SS / 64) STAGE(cur ^ 1, s0 + 64);   // prefetch next 64-s tile

#pragma unroll
    for (int ss = 0; ss < 2; ++ss) {
      const bf16* Kb = &Ks[cur][ss * 32 * 64];
      bf16x8 kf00 = *(const bf16x8*)(Kb + (l15)      * 64 + kswz0);
      bf16x8 kf01 = *(const bf16x8*)(Kb + (l15)      * 64 + kswz1);
      bf16x8 kf10 = *(const bf16x8*)(Kb + (16 + l15) * 64 + kswz0);
      bf16x8 kf11 = *(const bf16x8*)(Kb + (16 + l15) * 64 + kswz1);
      bf16x8 vf[4];
#pragma unroll
      for (int tt = 0; tt < 4; ++tt)
        vf[tt] = *(const bf16x8*)(&Vs[cur][0] + (tt * 16 + l15) * 64 +
                                  (((ss * 4 + quad) ^ (l15 & 7)) * 8));
      f32x4 mv0 = *(const f32x4*)(mrow + s0 + ss * 32 + quad * 4);
      f32x4 mv1 = *(const f32x4*)(mrow + s0 + ss * 32 + 16 + quad * 4);

#pragma unroll
      for (int mi = 0; mi < 2; ++mi) {
        f32x4 sc0 = zero4, sc1 = zero4;
        sc0 = __builtin_amdgcn_mfma_f32_16x16x32_bf16(kf00, qf[mi][0], sc0, 0, 0, 0);
        sc0 = __builtin_amdgcn_mfma_f32_16x16x32_bf16(kf01, qf[mi][1], sc0, 0, 0, 0);
        sc1 = __builtin_amdgcn_mfma_f32_16x16x32_bf16(kf10, qf[mi][0], sc1, 0, 0, 0);
        sc1 = __builtin_amdgcn_mfma_f32_16x16x32_bf16(kf11, qf[mi][1], sc1, 0, 0, 0);
        s4 pk0, pk1;
#pragma unroll
        for (int r = 0; r < 4; ++r) {
          float p = __expf(sc0[r] * 0.125f + mv0[r]);
          if (mi == 0) ps0 += p; else ps1 += p;
          pk0[r] = f2bs(p);
        }
#pragma unroll
        for (int r = 0; r < 4; ++r) {
          float p = __expf(sc1[r] * 0.125f + mv1[r]);
          if (mi == 0) ps0 += p; else ps1 += p;
          pk1[r] = f2bs(p);
        }
        *(s4*)&Plds[w][mi * 16 + l15][quad * 4] = pk0;
        *(s4*)&Plds[w][mi * 16 + l15][16 + quad * 4] = pk1;
      }
      asm volatile("" ::: "memory");   // all P-writes before cross-lane P-read
      bf16x8 pf0 = *(const bf16x8*)&Plds[w][l15][quad * 8];
      bf16x8 pf1 = *(const bf16x8*)&Plds[w][16 + l15][quad * 8];
#pragma unroll
      for (int tt = 0; tt < 4; ++tt) {
        o[0][tt] = __builtin_amdgcn_mfma_f32_16x16x32_bf16(pf0, vf[tt], o[0][tt], 0, 0, 0);
        o[1][tt] = __builtin_amdgcn_mfma_f32_16x16x32_bf16(pf1, vf[tt], o[1][tt], 0, 0, 0);
      }
      asm volatile("" ::: "memory");   // P-reads done before next subtile overwrites
    }
    __syncthreads();   // drains gll (next buf ready) + all waves done with cur
  }
#undef STAGE

  float lv0 = ps0; lv0 += __shfl_xor(lv0, 16, 64); lv0 += __shfl_xor(lv0, 32, 64);
  float lv1 = ps1; lv1 += __shfl_xor(lv1, 16, 64); lv1 += __shfl_xor(lv1, 32, 64);

#pragma unroll
  for (int mi = 0; mi < 2; ++mi) {
#pragma unroll
    for (int r = 0; r < 4; ++r) {
      float lv = (mi == 0) ? lv0 : lv1;
      float li = __shfl(lv, quad * 4 + r, 64);   // denom for q-row quad*4+r
      float inv = 1.0f / li;
      int q = q0 + mi * 16 + quad * 4 + r;
#pragma unroll
      for (int t = 0; t < 4; ++t) {
        float val = o[mi][t][r] * inv;
        ctx[(size_t)(q * 2 + b) * EE + (size_t)h * 64 + t * 16 + l15] = __float2bfloat16(val);
      }
    }
  }
}

extern "C" void kernel_launch(void* const* d_in, const int* in_sizes, int n_in,
                              void* d_out, int out_size, void* d_ws, size_t ws_size,
                              hipStream_t stream) {
  const float* query = (const float*)d_in[0];
  const float* key   = (const float*)d_in[1];
  const float* value = (const float*)d_in[2];
  const unsigned char* mask = (const unsigned char*)d_in[3];
  const float* Wq = (const float*)d_in[4];
  const float* bq = (const float*)d_in[5];
  const float* Wk = (const float*)d_in[6];
  const float* bk = (const float*)d_in[7];
  const float* Wv = (const float*)d_in[8];
  const float* bv = (const float*)d_in[9];
  const float* Wo = (const float*)d_in[10];
  const float* bo = (const float*)d_in[11];

  char* ws = (char*)d_ws;
  const bool big = ws_size >= ((size_t)41 << 20);

  // Layout A (small, <=33 MB): tab@0 | Qr@1M | Kr@9M | Vt@17M | ctx@25M
  // Layout B (big, 41 MB, = round-7 layout): tab@0 | Wb@1M (8) | Qr@9M |
  //   Kr@17M | Vt@25M | ctx@33M.
  // Xqb/Xkb (8 MB each) live in D_OUT (16 MB, dead until projo): prep writes,
  // qkv reads, projo overwrites — all stream-ordered.
  float2* tab   = (float2*)ws;                          // 512 KB
  float*  maskf = (float*)(ws + (512 << 10));           // 16 KB (inside tab's MB)
  bf16* Wb  = (bf16*)(ws + ((size_t)1 << 20));          // big only: 4 x 1M bf16
  size_t base = big ? ((size_t)9 << 20) : ((size_t)1 << 20);
  bf16* Qr  = (bf16*)(ws + base);                       // [b][h][l][d]
  bf16* Kr  = (bf16*)(ws + base + ((size_t)8 << 20));   // [b][h][s][d]
  bf16* Vt  = (bf16*)(ws + base + ((size_t)16 << 20));  // [b][h][d][s]
  bf16* ctx = (bf16*)(ws + base + ((size_t)24 << 20));
  bf16* Xqb = (bf16*)d_out;                             // 8 MB scratch in d_out
  bf16* Xkb = (bf16*)d_out + (size_t)MM * EE;           // next 8 MB

  prep_kernel<<<big ? 12560 : 272, 256, 0, stream>>>(
      tab, mask, maskf, Wq, Wk, Wv, Wo, Wb, query, key, Xqb, Xkb);

  if (big) {
    qkv_kernel<<<1536, 256, 0, stream>>>(Xqb, Xkb, value, Wb, bq, bk, bv,
                                         Qr, Kr, Vt, tab);
  } else {
    dim3 gp(MM / 128, EE / 64);
    proj_kernel<0, false, false><<<gp, 256, 0, stream>>>(query, Wq, bq, Qr, tab);
    proj_kernel<1, false, false><<<gp, 256, 0, stream>>>(key,   Wk, bk, Kr, tab);
    proj_kernel<2, false, false><<<gp, 256, 0, stream>>>(value, Wv, bv, Vt, tab);
  }

  attn_kernel<<<(LL / 128) * 2 * HH, 256, 0, stream>>>(Qr, Kr, Vt, maskf, ctx);

  if (big) {
    dim3 go(MM / 128, EE / 64);
    projo_kernel<<<go, 256, 0, stream>>>(ctx, Wb + (size_t)3 * EE * EE, bo, (float*)d_out);
  } else {
    dim3 gp(MM / 128, EE / 64);
    proj_kernel<3, true, false><<<gp, 256, 0, stream>>>(ctx, Wo, bo, d_out, tab);
  }
}

// Round 10
// 249.199 us; speedup vs baseline: 1.0604x; 1.0604x over previous
//
#include <hip/hip_runtime.h>
#include <hip/hip_bf16.h>

typedef __hip_bfloat16 bf16;
typedef short bf16x8 __attribute__((ext_vector_type(8)));   // 8 bf16 = 4 VGPRs (MFMA frag)
typedef float f32x4 __attribute__((ext_vector_type(4)));
typedef short s4 __attribute__((ext_vector_type(4)));

#define LL 2048
#define SS 2048
#define EE 1024
#define HH 16
#define HD 64
#define MM (LL * 2)   // 4096 rows (l*B+b)

static __device__ __forceinline__ short f2bs(float f) {
  bf16 h = __float2bfloat16(f);
  short u;
  __builtin_memcpy(&u, &h, 2);
  return u;
}

// pack 8 f32 -> bf16x8 and store to LDS (one ds_write_b128)
static __device__ __forceinline__ void st8(bf16* p, float4 x, float4 y) {
  bf16x8 v;
  v[0] = f2bs(x.x); v[1] = f2bs(x.y); v[2] = f2bs(x.z); v[3] = f2bs(x.w);
  v[4] = f2bs(y.x); v[5] = f2bs(y.y); v[6] = f2bs(y.z); v[7] = f2bs(y.w);
  *(bf16x8*)p = v;
}

// async global->LDS, 16B per lane. LDS dest must be wave-uniform base + lane*16.
#define GLL16(gp, lp) __builtin_amdgcn_global_load_lds(                        \
    (const __attribute__((address_space(1))) void*)(gp),                       \
    (__attribute__((address_space(3))) void*)(lp), 16, 0, 0)

// ---------------------------------------------------------------------------
// prep (round-7 form): tables (0..255) + mask (256..271) + 4x weight cvt
// (272..4367). Round-9's q/k input cvt REVERTED (qkv time was byte-invariant,
// so the +48 MB prep work was a pure loss).
__global__ __launch_bounds__(256) void prep_kernel(
    float2* __restrict__ tab, const unsigned char* __restrict__ m,
    float* __restrict__ mf,
    const float* __restrict__ s0, const float* __restrict__ s1,
    const float* __restrict__ s2, const float* __restrict__ s3,
    bf16* __restrict__ wdst) {
  const int bid = blockIdx.x;
  if (bid < 256) {
    int i = bid * 256 + threadIdx.x;   // 2048*32 entries
    int pos = i >> 5, fi = i & 31;
    float freq = expf(-(float)fi * (9.210340371976184f / 32.0f));  // 10000^(-fi/32)
    float ang = (float)pos * freq;
    float s, c;
    sincosf(ang, &s, &c);
    tab[i] = make_float2(c, s);
  } else if (bid < 272) {
    int i = (bid - 256) * 256 + threadIdx.x;
    if (i < 2 * SS) mf[i] = m[i] ? -1e30f : 0.f;
  } else {
    int b2 = bid - 272;
    int sel = b2 >> 10;
    const float* src = (sel == 0) ? s0 : (sel == 1) ? s1 : (sel == 2) ? s2 : s3;
    size_t loc = ((size_t)(b2 & 1023) * 256 + threadIdx.x) * 4;
    float4 v = *(const float4*)(src + loc);
    s4 p;
    p[0] = f2bs(v.x); p[1] = f2bs(v.y); p[2] = f2bs(v.z); p[3] = f2bs(v.w);
    *(s4*)(wdst + (size_t)sel * EE * EE + loc) = p;
  }
}

// ---------------------------------------------------------------------------
// OLD direct-from-global proj (kept only for the small-ws f32 fallback path).
template<int MODE, bool XB16, bool WB16>
__global__ __launch_bounds__(256) void proj_kernel(
    const void* __restrict__ Xv, const void* __restrict__ Wv,
    const float* __restrict__ bias, void* __restrict__ dstv,
    const float2* __restrict__ tab)
{
  const int w = threadIdx.x >> 6;
  const int lane = threadIdx.x & 63;
  const int l15 = lane & 15, quad = lane >> 4;
  const int tm = blockIdx.x * 128 + w * 32;
  const int tn = blockIdx.y * 64;

  const size_t aoff0 = (size_t)(tm + l15) * EE + quad * 8;
  const size_t aoff1 = aoff0 + (size_t)16 * EE;
  const size_t woff  = (size_t)(tn + l15) * EE + quad * 8;

  f32x4 zero4 = {0.f, 0.f, 0.f, 0.f};
  f32x4 acc[2][4];
#pragma unroll
  for (int mi = 0; mi < 2; ++mi)
#pragma unroll
    for (int ni = 0; ni < 4; ++ni) acc[mi][ni] = zero4;

  for (int k0 = 0; k0 < EE; k0 += 32) {
    bf16x8 a0, a1;
    if (XB16 || MODE == 3) {
      const bf16* Xb = (const bf16*)Xv;
      a0 = *(const bf16x8*)(Xb + aoff0 + k0);
      a1 = *(const bf16x8*)(Xb + aoff1 + k0);
    } else {
      const float* Xf = (const float*)Xv;
#pragma unroll
      for (int j = 0; j < 8; ++j) a0[j] = f2bs(Xf[aoff0 + k0 + j]);
#pragma unroll
      for (int j = 0; j < 8; ++j) a1[j] = f2bs(Xf[aoff1 + k0 + j]);
    }
#pragma unroll
    for (int ni = 0; ni < 4; ++ni) {
      bf16x8 bv;
      if (WB16) {
        const bf16* Wb = (const bf16*)Wv;
        bv = *(const bf16x8*)(Wb + woff + (size_t)ni * 16 * EE + k0);
      } else {
        const float* Wf = (const float*)Wv;
#pragma unroll
        for (int j = 0; j < 8; ++j) bv[j] = f2bs(Wf[woff + (size_t)ni * 16 * EE + k0 + j]);
      }
      acc[0][ni] = __builtin_amdgcn_mfma_f32_16x16x32_bf16(a0, bv, acc[0][ni], 0, 0, 0);
      acc[1][ni] = __builtin_amdgcn_mfma_f32_16x16x32_bf16(a1, bv, acc[1][ni], 0, 0, 0);
    }
  }

  float bz[4];
#pragma unroll
  for (int ni = 0; ni < 4; ++ni) bz[ni] = bias[tn + ni * 16 + l15];

#pragma unroll
  for (int mi = 0; mi < 2; ++mi) {
#pragma unroll
    for (int ni = 0; ni < 4; ++ni) {
      const int n = tn + ni * 16 + l15;
#pragma unroll
      for (int r = 0; r < 4; ++r) {
        const int m = tm + mi * 16 + quad * 4 + r;
        float v = acc[mi][ni][r] + bz[ni];
        if (MODE <= 1) {
          float other = __shfl_xor(v, 1, 64);        // pair element (n^1) is in lane^1
          int pos = m >> 1, b = m & 1, d = n & 63, h = n >> 6;
          float2 cs = tab[pos * 32 + (d >> 1)];
          float rv = (d & 1) ? (other * cs.y + v * cs.x) : (v * cs.x - other * cs.y);
          ((bf16*)dstv)[((size_t)(b * HH + h) * LL + pos) * HD + d] = __float2bfloat16(rv);
        } else if (MODE == 2) {
          int pos = m >> 1, b = m & 1, d = n & 63, h = n >> 6;
          ((bf16*)dstv)[((size_t)(b * HH + h) * HD + d) * SS + pos] = __float2bfloat16(v);
        } else {
          ((float*)dstv)[(size_t)m * EE + n] = v;
        }
      }
    }
  }
}

// ---------------------------------------------------------------------------
// Fused QKV — ROUND-7 VERSION verbatim (f32 A reg-staged for all three;
// round-9's bf16-A path reverted: qkv time was byte-invariant, so the extra
// prep pass was a net loss). 128m x 64n, BK=32, grid 1536 = 6/CU, packed
// zero-conflict LDS (slot(row,kc) = ((row&1)*4|kc) ^ ((row>>1)&7)).
__global__ __launch_bounds__(256, 6) void qkv_kernel(
    const float* __restrict__ Xq, const float* __restrict__ Xk,
    const float* __restrict__ Xv, const bf16* __restrict__ Wb,
    const float* __restrict__ bq, const float* __restrict__ bk,
    const float* __restrict__ bv, bf16* __restrict__ Qr,
    bf16* __restrict__ Kr, bf16* __restrict__ Vt,
    const float2* __restrict__ tab)
{
  __shared__ __align__(16) bf16 As[2][4096];   // 128 rows -> 64 lrows x 64 = 8 KB/buf
  __shared__ __align__(16) bf16 Bs[2][2048];   // 64 rows -> 32 lrows x 64 = 4 KB/buf

  const int tid = threadIdx.x;
  const int w = tid >> 6;
  const int lane = tid & 63;
  const int l15 = lane & 15, quad = lane >> 4;
  const int id = blockIdx.x;
  const int z = id >> 9;                 // 0=Q 1=K 2=V
  const int g = id & 511;
  const int tmb = (g & 31) * 128;        // same-A blocks (n varies) land on same XCD
  const int tn  = (g >> 5) * 64;

  const float* Xf = (z == 0) ? Xq : (z == 1) ? Xk : Xv;
  const bf16* Wm  = Wb + (size_t)z * EE * EE;
  const float* bias = (z == 0) ? bq : (z == 1) ? bk : bv;
  bf16* dst = (z == 0) ? Qr : (z == 1) ? Kr : Vt;

  // A staging: thread t covers rows ar and ar+64, k-chunk akc (8 f32).
  const int ar = tid >> 2;               // 0..63
  const int akc = tid & 3;
  const float* gA0 = Xf + (size_t)(tmb + ar) * EE + akc * 8;
  const float* gA1 = gA0 + (size_t)64 * EE;
  const int aw0 = (ar >> 1) * 64 + (((((ar & 1) << 2) | akc) ^ ((ar >> 1) & 7)) * 8);
  const int aw1 = aw0 + 2048;            // row+64 -> lrow+32, same &7 -> same slot

  // B staging: ONE gll/wave (16 n-rows = 8 lrows), pre-swizzled source.
  const int ub = (lane & 7) ^ (lane >> 3);
  const bf16* gB = Wm + (size_t)(tn + w * 16 + 2 * (lane >> 3) + (ub >> 2)) * EE
                      + (ub & 3) * 8;

  // fragment read base (A and B share the formula): row = 16*base + l15, kc = quad
  const int arbase = (l15 >> 1) * 64 + (((((l15 & 1) << 2) | quad) ^ (l15 >> 1)) * 8);

  f32x4 zero4 = {0.f, 0.f, 0.f, 0.f};
  f32x4 acc[2][4];
#pragma unroll
  for (int mi = 0; mi < 2; ++mi)
#pragma unroll
    for (int ni = 0; ni < 4; ++ni) acc[mi][ni] = zero4;

  {  // prologue: stage tile 0
    float4 a00 = *(const float4*)(gA0);
    float4 a01 = *(const float4*)(gA0 + 4);
    float4 a10 = *(const float4*)(gA1);
    float4 a11 = *(const float4*)(gA1 + 4);
    GLL16(gB, (bf16*)&Bs[0][w * 512] + lane * 8);
    st8(&As[0][aw0], a00, a01);
    st8(&As[0][aw1], a10, a11);
  }
  __syncthreads();

  for (int t = 0; t < 32; ++t) {
    const int cur = t & 1;
    float4 a00, a01, a10, a11;
    if (t < 31) {                        // issue next-tile loads EARLY (T14)
      const int k0 = (t + 1) * 32;
      a00 = *(const float4*)(gA0 + k0);
      a01 = *(const float4*)(gA0 + k0 + 4);
      a10 = *(const float4*)(gA1 + k0);
      a11 = *(const float4*)(gA1 + k0 + 4);
      GLL16(gB + k0, (bf16*)&Bs[cur ^ 1][w * 512] + lane * 8);
    }
    // compute current tile: 8 MFMA/wave (wave = 32m x 64n)
    bf16x8 af0 = *(const bf16x8*)(&As[cur][w * 1024 + arbase]);
    bf16x8 af1 = *(const bf16x8*)(&As[cur][w * 1024 + 512 + arbase]);
#pragma unroll
    for (int ni = 0; ni < 4; ++ni) {
      bf16x8 bfr = *(const bf16x8*)(&Bs[cur][ni * 512 + arbase]);
      acc[0][ni] = __builtin_amdgcn_mfma_f32_16x16x32_bf16(af0, bfr, acc[0][ni], 0, 0, 0);
      acc[1][ni] = __builtin_amdgcn_mfma_f32_16x16x32_bf16(af1, bfr, acc[1][ni], 0, 0, 0);
    }
    if (t < 31) {                        // write-late: cvt lands after compute
      st8(&As[cur ^ 1][aw0], a00, a01);
      st8(&As[cur ^ 1][aw1], a10, a11);
    }
    __syncthreads();                     // drains gll + ds_writes + reads
  }

  float bz[4];
#pragma unroll
  for (int ni = 0; ni < 4; ++ni) bz[ni] = bias[tn + ni * 16 + l15];

#pragma unroll
  for (int mi = 0; mi < 2; ++mi) {
#pragma unroll
    for (int ni = 0; ni < 4; ++ni) {
      const int n = tn + ni * 16 + l15;
#pragma unroll
      for (int r = 0; r < 4; ++r) {
        const int m = tmb + w * 32 + mi * 16 + quad * 4 + r;
        float v = acc[mi][ni][r] + bz[ni];
        if (z <= 1) {                    // RoPE epilogue (Q, K)
          float other = __shfl_xor(v, 1, 64);   // pair element (n^1) is in lane^1
          int pos = m >> 1, b = m & 1, d = n & 63, h = n >> 6;
          float2 cs = tab[pos * 32 + (d >> 1)];
          float rv = (d & 1) ? (other * cs.y + v * cs.x) : (v * cs.x - other * cs.y);
          dst[((size_t)(b * HH + h) * LL + pos) * HD + d] = __float2bfloat16(rv);
        } else {                         // V: store transposed [b][h][d][pos]
          int pos = m >> 1, b = m & 1, d = n & 63, h = n >> 6;
          dst[((size_t)(b * HH + h) * HD + d) * SS + pos] = __float2bfloat16(v);
        }
      }
    }
  }
}

// ---------------------------------------------------------------------------
// ROUND-10 O-projection: 64m x 64n tile, BK=64, grid (64,16) = 1024 =
// 4 blocks/CU (2x round-7's 2/CU — the proven blocks/CU throughput lever,
// last unexploited here). 8 MFMA/wave/iter (work/barrier unchanged), 16 iters
// (half the barriers). 128-B LDS rows with the attn-proven (row&7) XOR chunk
// swizzle (2-way, free); both operands gll with pre-swizzled source.
// LDS 32 KB/block -> 5/CU cap; grid gives 4/CU exactly.
__global__ __launch_bounds__(256, 4) void projo_kernel(
    const bf16* __restrict__ X, const bf16* __restrict__ W,
    const float* __restrict__ bias, float* __restrict__ dst)
{
  __shared__ __align__(16) bf16 As[2][64 * 64];    // 8 KB/buf
  __shared__ __align__(16) bf16 Bs[2][64 * 64];    // 8 KB/buf

  const int tid = threadIdx.x;
  const int w = tid >> 6;
  const int lane = tid & 63;
  const int l15 = lane & 15, quad = lane >> 4;
  const int tmb = blockIdx.x * 64;
  const int tn  = blockIdx.y * 64;

  // staging: wave w covers rows w*16..w*16+15 of A and B as 2 glls (8 rows,
  // 8 chunks each); source chunk pre-swizzled: c_global = (lane&7) ^ srow.
  const int srow = lane >> 3;                 // 0..7 == row&7 for every gll
  const int gswz = ((lane & 7) ^ srow) * 8;
  const bf16* gA0 = X + (size_t)(tmb + w * 16 + srow) * EE + gswz;
  const bf16* gA1 = gA0 + (size_t)8 * EE;
  const bf16* gB0 = W + (size_t)(tn + w * 16 + srow) * EE + gswz;
  const bf16* gB1 = gB0 + (size_t)8 * EE;

  // read-side swizzled chunk offsets (row&7 == l15&7 for all frag reads)
  const int ksw0 = ((quad    ) ^ (l15 & 7)) * 8;   // k-half 0 (k 0..31)
  const int ksw1 = ((quad + 4) ^ (l15 & 7)) * 8;   // k-half 1 (k 32..63)

  f32x4 zero4 = {0.f, 0.f, 0.f, 0.f};
  f32x4 acc[4];
#pragma unroll
  for (int ni = 0; ni < 4; ++ni) acc[ni] = zero4;

  GLL16(gA0, (bf16*)&As[0][(w * 16) * 64] + lane * 8);
  GLL16(gA1, (bf16*)&As[0][(w * 16 + 8) * 64] + lane * 8);
  GLL16(gB0, (bf16*)&Bs[0][(w * 16) * 64] + lane * 8);
  GLL16(gB1, (bf16*)&Bs[0][(w * 16 + 8) * 64] + lane * 8);
  __syncthreads();

  for (int t = 0; t < 16; ++t) {
    const int cur = t & 1;
    if (t < 15) {                        // prefetch next 64-K tile
      const int k0 = (t + 1) * 64;
      GLL16(gA0 + k0, (bf16*)&As[cur ^ 1][(w * 16) * 64] + lane * 8);
      GLL16(gA1 + k0, (bf16*)&As[cur ^ 1][(w * 16 + 8) * 64] + lane * 8);
      GLL16(gB0 + k0, (bf16*)&Bs[cur ^ 1][(w * 16) * 64] + lane * 8);
      GLL16(gB1 + k0, (bf16*)&Bs[cur ^ 1][(w * 16 + 8) * 64] + lane * 8);
    }
    // 8 MFMA/wave: 2 k-halves x 4 n-frags; wave = 16m x 64n
    bf16x8 a0 = *(const bf16x8*)(&As[cur][(w * 16 + l15) * 64 + ksw0]);
    bf16x8 a1 = *(const bf16x8*)(&As[cur][(w * 16 + l15) * 64 + ksw1]);
#pragma unroll
    for (int ni = 0; ni < 4; ++ni) {
      bf16x8 b0 = *(const bf16x8*)(&Bs[cur][(ni * 16 + l15) * 64 + ksw0]);
      bf16x8 b1 = *(const bf16x8*)(&Bs[cur][(ni * 16 + l15) * 64 + ksw1]);
      acc[ni] = __builtin_amdgcn_mfma_f32_16x16x32_bf16(a0, b0, acc[ni], 0, 0, 0);
      acc[ni] = __builtin_amdgcn_mfma_f32_16x16x32_bf16(a1, b1, acc[ni], 0, 0, 0);
    }
    __syncthreads();
  }

  float bz[4];
#pragma unroll
  for (int ni = 0; ni < 4; ++ni) bz[ni] = bias[tn + ni * 16 + l15];

#pragma unroll
  for (int ni = 0; ni < 4; ++ni) {
    const int n = tn + ni * 16 + l15;
#pragma unroll
    for (int r = 0; r < 4; ++r) {
      const int m = tmb + w * 16 + quad * 4 + r;
      dst[(size_t)m * EE + n] = acc[ni][r] + bz[ni];
    }
  }
}

// ---------------------------------------------------------------------------
// Flash attention — ROUND-7 16q/wave version (grid 1024 = 4 blocks/CU;
// cross-round subtraction shows it ~4.6 µs faster than the 32q version).
__global__ __launch_bounds__(256, 4) void attn_kernel(
    const bf16* __restrict__ Qr, const bf16* __restrict__ Kr,
    const bf16* __restrict__ Vt, const float* __restrict__ maskf,
    bf16* __restrict__ ctx)
{
  __shared__ __align__(16) bf16 Ks[2][64 * 64];       // 16 KB: [buf][s][d]
  __shared__ __align__(16) bf16 Vs[2][64 * 64];       // 16 KB: [buf][d][s]
  __shared__ __align__(16) short Plds[4][16][56];     // 7 KB: [wave][q][s str 56]

  const int w = threadIdx.x >> 6;
  const int lane = threadIdx.x & 63;
  const int l15 = lane & 15, quad = lane >> 4;
  const int id = blockIdx.x;
  const int bh = id & 31;             // XCD = bh % 8
  const int qt = id >> 5;             // 0..31
  const int b = bh >> 4, h = bh & 15;
  const int q0 = qt * 64 + w * 16;

  const bf16* Qbh = Qr + (size_t)bh * LL * HD;
  const bf16* Kbh = Kr + (size_t)bh * SS * HD;
  const bf16* Vbh = Vt + (size_t)bh * HD * SS;
  const float* mrow = maskf + b * SS;

  bf16x8 qf0, qf1;
  {
    const bf16* qp = Qbh + (size_t)(q0 + l15) * HD + quad * 8;
    qf0 = *(const bf16x8*)(qp);
    qf1 = *(const bf16x8*)(qp + 32);
  }

  const int srow = lane >> 3;                     // 0..7
  const int gswz = ((lane & 7) ^ srow) * 8;       // source chunk, elems
  const int kswz0 = ((quad    ) ^ (l15 & 7)) * 8;
  const int kswz1 = ((quad + 4) ^ (l15 & 7)) * 8;

#define STAGE(buf, S0) {                                                       \
    _Pragma("unroll")                                                          \
    for (int i = 0; i < 2; ++i) {                                              \
      const int rb = w * 16 + i * 8;                                           \
      GLL16(Kbh + (size_t)((S0) + rb + srow) * HD + gswz,                      \
            (bf16*)&Ks[buf][rb * 64] + lane * 8);                              \
      GLL16(Vbh + (size_t)(rb + srow) * SS + (S0) + gswz,                      \
            (bf16*)&Vs[buf][rb * 64] + lane * 8);                              \
    }                                                                          \
  }

  f32x4 zero4 = {0.f, 0.f, 0.f, 0.f};
  f32x4 o[4];
#pragma unroll
  for (int t = 0; t < 4; ++t) o[t] = zero4;
  float ps = 0.f;

  STAGE(0, 0);
  __syncthreads();

  for (int t = 0; t < SS / 64; ++t) {
    const int s0 = t * 64;
    const int cur = t & 1;
    if (t + 1 < SS / 64) STAGE(cur ^ 1, s0 + 64);   // prefetch next 64-s tile

#pragma unroll
    for (int ss = 0; ss < 2; ++ss) {
      const bf16* Kb = &Ks[cur][ss * 32 * 64];
      bf16x8 kf00 = *(const bf16x8*)(Kb + (l15)      * 64 + kswz0);
      bf16x8 kf01 = *(const bf16x8*)(Kb + (l15)      * 64 + kswz1);
      bf16x8 kf10 = *(const bf16x8*)(Kb + (16 + l15) * 64 + kswz0);
      bf16x8 kf11 = *(const bf16x8*)(Kb + (16 + l15) * 64 + kswz1);
      bf16x8 vf[4];
#pragma unroll
      for (int tt = 0; tt < 4; ++tt)
        vf[tt] = *(const bf16x8*)(&Vs[cur][0] + (tt * 16 + l15) * 64 +
                                  (((ss * 4 + quad) ^ (l15 & 7)) * 8));
      f32x4 mv0 = *(const f32x4*)(mrow + s0 + ss * 32 + quad * 4);
      f32x4 mv1 = *(const f32x4*)(mrow + s0 + ss * 32 + 16 + quad * 4);

      // S^T = K.Q^T: C row = s_local (quad*4+r), C col = q_local (l15)
      f32x4 sc0 = zero4, sc1 = zero4;
      sc0 = __builtin_amdgcn_mfma_f32_16x16x32_bf16(kf00, qf0, sc0, 0, 0, 0);
      sc0 = __builtin_amdgcn_mfma_f32_16x16x32_bf16(kf01, qf1, sc0, 0, 0, 0);
      sc1 = __builtin_amdgcn_mfma_f32_16x16x32_bf16(kf10, qf0, sc1, 0, 0, 0);
      sc1 = __builtin_amdgcn_mfma_f32_16x16x32_bf16(kf11, qf1, sc1, 0, 0, 0);
      s4 pk0, pk1;
#pragma unroll
      for (int r = 0; r < 4; ++r) {
        float p = __expf(sc0[r] * 0.125f + mv0[r]);
        ps += p; pk0[r] = f2bs(p);
      }
#pragma unroll
      for (int r = 0; r < 4; ++r) {
        float p = __expf(sc1[r] * 0.125f + mv1[r]);
        ps += p; pk1[r] = f2bs(p);
      }
      *(s4*)&Plds[w][l15][quad * 4] = pk0;
      *(s4*)&Plds[w][l15][16 + quad * 4] = pk1;
      asm volatile("" ::: "memory");   // all P-writes before cross-lane P-read
      bf16x8 pf = *(const bf16x8*)&Plds[w][l15][quad * 8];
#pragma unroll
      for (int tt = 0; tt < 4; ++tt)
        o[tt] = __builtin_amdgcn_mfma_f32_16x16x32_bf16(pf, vf[tt], o[tt], 0, 0, 0);
      asm volatile("" ::: "memory");   // P-reads done before next subtile overwrites
    }
    __syncthreads();   // drains gll (next buf ready) + all waves done with cur
  }
#undef STAGE

  // softmax denominator: lane holds partial for q-col l15, s rows quad*4+r
  float lv = ps;
  lv += __shfl_xor(lv, 16, 64);
  lv += __shfl_xor(lv, 32, 64);

#pragma unroll
  for (int r = 0; r < 4; ++r) {
    float li = __shfl(lv, quad * 4 + r, 64);   // denom for q-row quad*4+r
    float inv = 1.0f / li;
    int q = q0 + quad * 4 + r;
#pragma unroll
    for (int t = 0; t < 4; ++t) {
      float val = o[t][r] * inv;
      ctx[(size_t)(q * 2 + b) * EE + (size_t)h * 64 + t * 16 + l15] = __float2bfloat16(val);
    }
  }
}

extern "C" void kernel_launch(void* const* d_in, const int* in_sizes, int n_in,
                              void* d_out, int out_size, void* d_ws, size_t ws_size,
                              hipStream_t stream) {
  const float* query = (const float*)d_in[0];
  const float* key   = (const float*)d_in[1];
  const float* value = (const float*)d_in[2];
  const unsigned char* mask = (const unsigned char*)d_in[3];
  const float* Wq = (const float*)d_in[4];
  const float* bq = (const float*)d_in[5];
  const float* Wk = (const float*)d_in[6];
  const float* bk = (const float*)d_in[7];
  const float* Wv = (const float*)d_in[8];
  const float* bv = (const float*)d_in[9];
  const float* Wo = (const float*)d_in[10];
  const float* bo = (const float*)d_in[11];

  char* ws = (char*)d_ws;
  const bool big = ws_size >= ((size_t)41 << 20);

  // Layout A (small, <=33 MB): tab@0 | Qr@1M | Kr@9M | Vt@17M | ctx@25M
  // Layout B (big, 41 MB, round-7 layout): tab@0 | Wb@1M (8) | Qr@9M |
  //   Kr@17M | Vt@25M | ctx@33M
  float2* tab   = (float2*)ws;                          // 512 KB
  float*  maskf = (float*)(ws + (512 << 10));           // 16 KB (inside tab's MB)
  bf16* Wb  = (bf16*)(ws + ((size_t)1 << 20));          // big only: 4 x 1M bf16
  size_t base = big ? ((size_t)9 << 20) : ((size_t)1 << 20);
  bf16* Qr  = (bf16*)(ws + base);                       // [b][h][l][d]
  bf16* Kr  = (bf16*)(ws + base + ((size_t)8 << 20));   // [b][h][s][d]
  bf16* Vt  = (bf16*)(ws + base + ((size_t)16 << 20));  // [b][h][d][s]
  bf16* ctx = (bf16*)(ws + base + ((size_t)24 << 20));

  prep_kernel<<<big ? 4368 : 272, 256, 0, stream>>>(
      tab, mask, maskf, Wq, Wk, Wv, Wo, Wb);

  if (big) {
    qkv_kernel<<<1536, 256, 0, stream>>>(query, key, value, Wb, bq, bk, bv,
                                         Qr, Kr, Vt, tab);
  } else {
    dim3 gp(MM / 128, EE / 64);
    proj_kernel<0, false, false><<<gp, 256, 0, stream>>>(query, Wq, bq, Qr, tab);
    proj_kernel<1, false, false><<<gp, 256, 0, stream>>>(key,   Wk, bk, Kr, tab);
    proj_kernel<2, false, false><<<gp, 256, 0, stream>>>(value, Wv, bv, Vt, tab);
  }

  attn_kernel<<<(LL / 64) * 2 * HH, 256, 0, stream>>>(Qr, Kr, Vt, maskf, ctx);

  if (big) {
    dim3 go(MM / 64, EE / 64);
    projo_kernel<<<go, 256, 0, stream>>>(ctx, Wb + (size_t)3 * EE * EE, bo, (float*)d_out);
  } else {
    dim3 gp(MM / 128, EE / 64);
    proj_kernel<3, true, false><<<gp, 256, 0, stream>>>(ctx, Wo, bo, d_out, tab);
  }
}